// Round 6
// baseline (94.310 us; speedup 1.0000x reference)
//
#include <hip/hip_runtime.h>
#include <math.h>

#define MB_    32
#define ATOM_  64
#define HID_   64
#define NRBF_  300
#define GAMMA_ 10.0f
#define RES_   0.1f

// filter table: f2(d) sampled at TPTS points, step TSTEP, domain [0, 10]
#define TPTS      2001
#define TSTEP     0.005f
#define INV_TSTEP 200.0f

// truncated RBF window: terms with |d - 0.1 r| > ~1.4 contribute < 5e-9
#define RWIN 28

// workspace layout (float offsets)
#define T_OFF   0
#define T_SZ    (TPTS * 64)          // 128064
#define V1_OFF  (T_OFF + T_SZ)       // 128064
#define V1_SZ   (MB_ * 64 * 64)      // 131072
#define W2T_OFF (V1_OFF + V1_SZ)     // 259136
#define W3T_OFF (W2T_OFF + 4096)     // 263232
// total 267328 floats = 1,069,312 bytes of d_ws

__device__ __forceinline__ float sp_f(float x) {
    return fmaxf(x, 0.f) + log1pf(__expf(-fabsf(x)));
}

// ---------------------------------------------------------------------------
// prep: blocks [0,32)   -> v1[m] = x[m] @ W1^T + b1   (4x4 register tile)
//       blocks [32,533) -> filter table rows, truncated-RBF, barrier-light
//       block  533      -> W2^T, W3^T for coalesced tail reads
// (unchanged from R5 — proven fast enough to leave top-5)
// ---------------------------------------------------------------------------
__global__ __launch_bounds__(256)
void schnet_prep(const float* __restrict__ x,   const float* __restrict__ W1,
                 const float* __restrict__ b1,  const float* __restrict__ W2,
                 const float* __restrict__ W3,  const float* __restrict__ Wd1,
                 const float* __restrict__ bd1, const float* __restrict__ Wd2,
                 const float* __restrict__ bd2, float* __restrict__ ws)
{
    __shared__ float smem[8320];     // 33.3 KB, unioned between branches
    const int tid = threadIdx.x;
    const int b   = blockIdx.x;

    if (b < MB_) {
        // ---- v1 = x[m] @ W1^T + b1, 4x4 register tile per thread ----
        float* sx = smem;            // x[m]  [64][65]
        float* sw = smem + 4160;     // W1    [64][65]
        const float* xm = x + b * 4096;
        for (int e = tid; e < 4096; e += 256) {
            int i = e >> 6, c = e & 63;
            sx[i * 65 + c] = xm[e];
            sw[i * 65 + c] = W1[e];
        }
        __syncthreads();
        const int tx = tid & 15;
        const int ty = tid >> 4;
        float acc[4][4];
        #pragma unroll
        for (int aa = 0; aa < 4; ++aa)
            #pragma unroll
            for (int bb = 0; bb < 4; ++bb)
                acc[aa][bb] = b1[4 * tx + bb];
        #pragma unroll 8
        for (int k = 0; k < 64; ++k) {
            float xa[4], wb[4];
            #pragma unroll
            for (int aa = 0; aa < 4; ++aa) xa[aa] = sx[(4 * ty + aa) * 65 + k];
            #pragma unroll
            for (int bb = 0; bb < 4; ++bb) wb[bb] = sw[(4 * tx + bb) * 65 + k];
            #pragma unroll
            for (int aa = 0; aa < 4; ++aa)
                #pragma unroll
                for (int bb = 0; bb < 4; ++bb)
                    acc[aa][bb] = fmaf(xa[aa], wb[bb], acc[aa][bb]);
        }
        #pragma unroll
        for (int aa = 0; aa < 4; ++aa) {
            float4 v = make_float4(acc[aa][0], acc[aa][1], acc[aa][2], acc[aa][3]);
            *(float4*)(ws + V1_OFF + (b * 64 + 4 * ty + aa) * 64 + 4 * tx) = v;
        }
    } else if (b < MB_ + 501) {
        // ---- table: one d-sample per wave, truncated RBF in registers ----
        float* su = smem;                // [4][64]
        const int sub = tid >> 6, c = tid & 63;
        const int s  = (b - MB_) * 4 + sub;
        const int se = min(s, TPTS - 1);
        const float d = se * TSTEP;

        int r0 = (int)ceilf((d - 1.35f) * 10.0f);
        r0 = max(r0, 0);

        float a0 = bd1[c], a1 = 0.f;
        const float* wrow1 = Wd1 + c * NRBF_ + r0;
        #pragma unroll
        for (int k = 0; k < RWIN; k += 2) {
            float t0 = fmaf(-RES_, (float)(r0 + k),     d);
            float t1 = fmaf(-RES_, (float)(r0 + k + 1), d);
            float w0 = __expf(-GAMMA_ * t0 * t0);
            float w1 = __expf(-GAMMA_ * t1 * t1);
            a0 = fmaf(w0, wrow1[k],     a0);
            a1 = fmaf(w1, wrow1[k + 1], a1);
        }
        su[sub * 64 + c] = sp_f(a0 + a1);
        __syncthreads();

        const float4* wrow2 = (const float4*)(Wd2 + c * 64);
        const float*  uu    = su + sub * 64;
        float s0 = bd2[c], s1 = 0.f, s2 = 0.f, s3 = 0.f;
        #pragma unroll
        for (int h4 = 0; h4 < 16; ++h4) {
            float4 wv = wrow2[h4];
            s0 = fmaf(wv.x, uu[4 * h4 + 0], s0);
            s1 = fmaf(wv.y, uu[4 * h4 + 1], s1);
            s2 = fmaf(wv.z, uu[4 * h4 + 2], s2);
            s3 = fmaf(wv.w, uu[4 * h4 + 3], s3);
        }
        if (s < TPTS)
            ws[T_OFF + s * 64 + c] = sp_f((s0 + s1) + (s2 + s3));
    } else {
        // ---- transpose W2, W3 ----
        for (int e = tid; e < 4096; e += 256) {
            int o = e >> 6, c = e & 63;
            ws[W2T_OFF + c * 64 + o] = W2[e];
            ws[W3T_OFF + c * 64 + o] = W3[e];
        }
    }
}

// ---------------------------------------------------------------------------
// main: one block per (m, group of 4 j).  Wave p owns j = 4*bj + p fully:
//   agg[c] = sum_i v1[m,i,c] * lerp(T, d_ij)[c]   (in-wave, no reduction)
//   v2 = sp(agg @ W2^T + b2); out = x + v2 @ W3^T + b3  (full-wave matvecs)
// ---------------------------------------------------------------------------
__global__ __launch_bounds__(256)
void schnet_main(const float* __restrict__ x, const float* __restrict__ dist,
                 const float* __restrict__ b2, const float* __restrict__ b3,
                 const float* __restrict__ ws, float* __restrict__ out)
{
    __shared__ float sDist[64 * 4];  // [i][jj]
    __shared__ float sAgg [4 * 64];  // per-wave agg vector
    __shared__ float sV   [4 * 64];  // per-wave v2 vector
    const int m   = blockIdx.x >> 4;
    const int j0  = (blockIdx.x & 15) * 4;
    const int tid = threadIdx.x;
    const int c   = tid & 63;        // channel / output lane
    const int p   = tid >> 6;        // wave id -> j = j0 + p

    // stage the 64x4 dist sub-block: thread t<64 loads row i=t, cols j0..j0+3
    if (tid < 64) {
        float4 dv = *(const float4*)(dist + (m * ATOM_ + tid) * ATOM_ + j0);
        *(float4*)(sDist + tid * 4) = dv;
    }
    __syncthreads();

    const float* Tb  = ws + T_OFF;
    const float* v1m = ws + V1_OFF + m * 4096;
    float acc = 0.f;
    #pragma unroll 8
    for (int ii = 0; ii < 64; ++ii) {
        float d  = sDist[ii * 4 + p];               // LDS broadcast (wave-uniform)
        float f  = d * INV_TSTEP;
        int   s  = min((int)f, TPTS - 2);
        float fr = f - (float)s;
        const float* Tr = Tb + s * 64;
        float t0 = Tr[c], t1 = Tr[64 + c];          // coalesced 256B rows
        float f2v = fmaf(fr, t1 - t0, t0);
        acc = fmaf(f2v, v1m[ii * 64 + c], acc);     // same row all 4 waves -> L1
    }
    sAgg[p * 64 + c] = acc;
    __syncthreads();

    // v2[c] = sp( sum_cc agg[cc] * W2t[cc][c] + b2[c] )  — per-wave matvec
    {
        const float* W2t = ws + W2T_OFF;
        const float* ag  = sAgg + p * 64;
        float s0 = b2[c], s1 = 0.f;
        #pragma unroll 16
        for (int cc = 0; cc < 64; cc += 2) {
            s0 = fmaf(ag[cc],     W2t[cc * 64 + c],       s0);   // ag: broadcast
            s1 = fmaf(ag[cc + 1], W2t[(cc + 1) * 64 + c], s1);   // W2t: coalesced
        }
        sV[p * 64 + c] = sp_f(s0 + s1);
    }
    __syncthreads();

    // v3[c] = sum_oo v2[oo] * W3t[oo][c] + b3[c];  out = x + v3
    {
        const float* W3t = ws + W3T_OFF;
        const float* vv  = sV + p * 64;
        float s0 = b3[c], s1 = 0.f;
        #pragma unroll 16
        for (int oo = 0; oo < 64; oo += 2) {
            s0 = fmaf(vv[oo],     W3t[oo * 64 + c],       s0);
            s1 = fmaf(vv[oo + 1], W3t[(oo + 1) * 64 + c], s1);
        }
        const int idx = (m * ATOM_ + j0 + p) * HID_ + c;
        out[idx] = (s0 + s1) + x[idx];
    }
}

extern "C" void kernel_launch(void* const* d_in, const int* in_sizes, int n_in,
                              void* d_out, int out_size, void* d_ws, size_t ws_size,
                              hipStream_t stream) {
    const float* x   = (const float*)d_in[0];
    const float* dist= (const float*)d_in[1];
    const float* W1  = (const float*)d_in[2];
    const float* b1  = (const float*)d_in[3];
    const float* W2  = (const float*)d_in[4];
    const float* b2  = (const float*)d_in[5];
    const float* W3  = (const float*)d_in[6];
    const float* b3  = (const float*)d_in[7];
    const float* Wd1 = (const float*)d_in[8];
    const float* bd1 = (const float*)d_in[9];
    const float* Wd2 = (const float*)d_in[10];
    const float* bd2 = (const float*)d_in[11];
    float* out = (float*)d_out;
    float* ws  = (float*)d_ws;
    (void)in_sizes; (void)n_in; (void)out_size; (void)ws_size;
    // needs ~1.07 MB of d_ws (table + v1 + W2^T/W3^T)

    schnet_prep<<<dim3(MB_ + 501 + 1), dim3(256), 0, stream>>>(
        x, W1, b1, W2, W3, Wd1, bd1, Wd2, bd2, ws);
    schnet_main<<<dim3(MB_ * 16), dim3(256), 0, stream>>>(
        x, dist, b2, b3, ws, out);
}